// Round 8
// baseline (394.625 us; speedup 1.0000x reference)
//
#include <hip/hip_runtime.h>
#include <hip/hip_fp16.h>
#include <float.h>

#define DIMD   128
#define KCODES 1024
#define NROWS  65536
#define TAU    0.03f
#define SEG_R  16    // rows per segsum group

typedef __attribute__((ext_vector_type(8)))  _Float16 half8;
typedef __attribute__((ext_vector_type(16))) float f32x16;

union U8 { uint4 u; half8 h; };

__device__ __forceinline__ unsigned packh2(float a, float b) {
    __half2 t = __floats2half2_rn(a, b);
    return *(unsigned*)&t;
}

// ---- fused: preconvert codebook f16-hi (blocks 0..63) + enorm (64..67) + zero counts (68) ----
__global__ __launch_bounds__(256) void pre_kernel(
    const float* __restrict__ embed, uint4* __restrict__ ehg,
    float* __restrict__ enorm, uint4* __restrict__ zero_region)
{
    if (blockIdx.x < 64) {
        int t = blockIdx.x * 256 + threadIdx.x;     // 0..16383
        int chunk = t >> 9;
        int s = (t >> 6) & 7;
        int L = t & 63;
        const float* src = embed + ((size_t)(chunk * 32 + (L & 31)) * DIMD) + s * 16 + (L >> 5) * 8;
        float4 a = *(const float4*)src;
        float4 b = *(const float4*)(src + 4);
        float f[8] = {a.x, a.y, a.z, a.w, b.x, b.y, b.z, b.w};
        uint4 H;
        unsigned* hw = (unsigned*)&H;
#pragma unroll
        for (int j = 0; j < 4; ++j) hw[j] = packh2(f[2 * j], f[2 * j + 1]);
        ehg[t] = H;
    } else if (blockIdx.x < 68) {
        int k = (blockIdx.x - 64) * 256 + threadIdx.x;
        const float4* e = (const float4*)(embed + (size_t)k * DIMD);
        float s = 0.f;
#pragma unroll
        for (int c = 0; c < DIMD / 4; ++c) {
            float4 v = e[c];
            s += v.x * v.x + v.y * v.y + v.z * v.z + v.w * v.w;
        }
        enorm[k] = s;
    } else {
        uint4 z = {0, 0, 0, 0};
        zero_region[threadIdx.x] = z;
        zero_region[threadIdx.x + 256] = z;
    }
}

// ---------------- fused MFMA distance (f16 2-term: (xh+xl)·eh) + argmin (top-2) ----------------
__global__ __launch_bounds__(256, 3) void argmin_mfma(
    const float* __restrict__ x, const uint4* __restrict__ ehg,
    const float* __restrict__ enorm,
    int* __restrict__ ind_i, float* __restrict__ ind_f,
    int* __restrict__ wl, int* __restrict__ wl_cnt)
{
    __shared__ uint4 Bs[512];     // one chunk of eh f16 frags (8 KB)

    const int tid  = threadIdx.x;
    const int wave = tid >> 6;
    const int lane = tid & 63;
    const int n    = lane & 31;
    const int h    = lane >> 5;
    const int row0 = blockIdx.x * 128;
    const int rowA = row0 + wave * 32 + n;

    // A fragments: x split into f16 hi/lo, held in regs for all 8 k-steps
    uint4 xh[8], xl[8];
    const float* xrow = x + (size_t)rowA * DIMD + h * 8;
#pragma unroll
    for (int s = 0; s < 8; ++s) {
        float4 a = *(const float4*)(xrow + s * 16);
        float4 b = *(const float4*)(xrow + s * 16 + 4);
        float f[8] = {a.x, a.y, a.z, a.w, b.x, b.y, b.z, b.w};
        unsigned* ph = (unsigned*)&xh[s];
        unsigned* pl = (unsigned*)&xl[s];
#pragma unroll
        for (int j = 0; j < 4; ++j) {
            float u0 = f[2 * j], u1 = f[2 * j + 1];
            __half2 hh = __floats2half2_rn(u0, u1);
            ph[j] = *(unsigned*)&hh;
            float2 back = __half22float2(hh);
            __half2 ll = __floats2half2_rn(u0 - back.x, u1 - back.y);
            pl[j] = *(unsigned*)&ll;
        }
    }

    float bestv[16], best2[16];
    int   besti[16];
#pragma unroll
    for (int r = 0; r < 16; ++r) { bestv[r] = FLT_MAX; best2[r] = FLT_MAX; besti[r] = 0; }

    for (int chunk = 0; chunk < KCODES / 32; ++chunk) {
        __syncthreads();   // previous chunk's Bs reads done
        {
            const uint4* sh = ehg + chunk * 512;
            Bs[tid]       = sh[tid];
            Bs[tid + 256] = sh[tid + 256];
        }
        float ee_val = enorm[chunk * 32 + n];
        __syncthreads();

        f32x16 acc;
#pragma unroll
        for (int r = 0; r < 16; ++r) acc[r] = 0.f;

#pragma unroll
        for (int s = 0; s < 8; ++s) {
            U8 ah, al, bh;
            ah.u = xh[s]; al.u = xl[s];
            bh.u = Bs[s * 64 + lane];
            acc = __builtin_amdgcn_mfma_f32_32x32x16_f16(ah.h, bh.h, acc, 0, 0, 0);
            acc = __builtin_amdgcn_mfma_f32_32x32x16_f16(al.h, bh.h, acc, 0, 0, 0);
        }

        const int nglob = chunk * 32 + n;
#pragma unroll
        for (int r = 0; r < 16; ++r) {
            float d = fmaf(-2.f, acc[r], ee_val);
            bool c1 = d < bestv[r];
            float t = c1 ? bestv[r] : d;
            best2[r] = fminf(best2[r], t);
            besti[r] = c1 ? nglob : besti[r];
            bestv[r] = fminf(bestv[r], d);
        }
    }

    // cross-lane (32 columns) top-2 merge via butterfly
#pragma unroll
    for (int m = 1; m <= 16; m <<= 1) {
#pragma unroll
        for (int r = 0; r < 16; ++r) {
            float ov = __shfl_xor(bestv[r], m, 64);
            float o2 = __shfl_xor(best2[r], m, 64);
            int   oi = __shfl_xor(besti[r], m, 64);
            float hi = fmaxf(bestv[r], ov);
            best2[r] = fminf(fminf(best2[r], o2), hi);
            bool take = (ov < bestv[r]) || (ov == bestv[r] && oi < besti[r]);
            bestv[r] = take ? ov : bestv[r];
            besti[r] = take ? oi : besti[r];
        }
    }

    if (n == 0) {
#pragma unroll
        for (int r = 0; r < 16; ++r) {
            int row = row0 + wave * 32 + (r & 3) + 8 * (r >> 2) + 4 * h;
            ind_i[row] = besti[r];
            ind_f[row] = (float)besti[r];
            if (best2[r] - bestv[r] < TAU) {
                int p = atomicAdd(wl_cnt, 1);
                if (p < NROWS) wl[p] = row;
            }
        }
    }
}

// ---------------- exact fp32 re-check for near-tie rows (fixes ind only) ----------------
__global__ __launch_bounds__(256) void recheck_kernel(
    const float* __restrict__ x, const float* __restrict__ embed,
    const float* __restrict__ enorm, const int* __restrict__ wl,
    const int* __restrict__ wl_cnt, int* __restrict__ ind_i, float* __restrict__ ind_f)
{
    __shared__ float xs[DIMD];
    __shared__ float rv[256];
    __shared__ int   ri[256];
    const int tid = threadIdx.x;
    int count = *wl_cnt;
    if (count > NROWS) count = NROWS;

    for (int i = blockIdx.x; i < count; i += gridDim.x) {
        const int row = wl[i];
        __syncthreads();
        if (tid < DIMD) xs[tid] = x[(size_t)row * DIMD + tid];
        __syncthreads();

        const float4* xs4 = (const float4*)xs;
        float xn = 0.f;
#pragma unroll 8
        for (int c = 0; c < 32; ++c) {
            float4 v = xs4[c];
            xn += v.x * v.x + v.y * v.y + v.z * v.z + v.w * v.w;
        }

        float bv = FLT_MAX; int bi = 0;
#pragma unroll
        for (int c = 0; c < 4; ++c) {
            int code = tid * 4 + c;
            const float4* er = (const float4*)(embed + (size_t)code * DIMD);
            float acc = 0.f;
#pragma unroll 8
            for (int kk = 0; kk < 32; ++kk) {
                float4 a = xs4[kk];
                float4 b = er[kk];
                acc += a.x * b.x + a.y * b.y + a.z * b.z + a.w * b.w;
            }
            float d = (xn - 2.0f * acc) + enorm[code];
            if (d < bv) { bv = d; bi = code; }
        }
        rv[tid] = bv; ri[tid] = bi;
        __syncthreads();
        for (int s = 128; s > 0; s >>= 1) {
            if (tid < s) {
                if (rv[tid + s] < rv[tid] || (rv[tid + s] == rv[tid] && ri[tid + s] < ri[tid])) {
                    rv[tid] = rv[tid + s]; ri[tid] = ri[tid + s];
                }
            }
            __syncthreads();
        }
        if (tid == 0) {
            int s_new = ri[0];
            if (s_new != ind_i[row]) {
                ind_i[row] = s_new;
                ind_f[row] = (float)s_new;
            }
        }
        __syncthreads();
    }
}

// ---------------- histogram of final code assignments (LDS-aggregated) ----------------
__global__ __launch_bounds__(256) void hist_kernel(
    const int* __restrict__ ind, int* __restrict__ counts)
{
    __shared__ int hcnt[KCODES];
    for (int i = threadIdx.x; i < KCODES; i += 256) hcnt[i] = 0;
    __syncthreads();
    const int base = blockIdx.x * 2048;
    for (int i = threadIdx.x; i < 2048; i += 256) atomicAdd(&hcnt[ind[base + i]], 1);
    __syncthreads();
    for (int i = threadIdx.x; i < KCODES; i += 256) {
        int v = hcnt[i];
        if (v) atomicAdd(&counts[i], v);
    }
}

// ---------------- fused: exclusive scan (cursor) + cluster EMA + smoothed ----------------
__global__ __launch_bounds__(1024) void scan_cluster_kernel(
    const int* __restrict__ counts, const float* __restrict__ cluster_size,
    int* __restrict__ cursor, float* __restrict__ out_cs, float* __restrict__ smoothed)
{
    __shared__ int   s[KCODES];
    __shared__ float rf[KCODES];
    const int t = threadIdx.x;
    int my = counts[t];
    s[t] = my;
    float cs = cluster_size[t] * 0.99f + (float)my * 0.01f;
    out_cs[t] = cs;
    rf[t] = cs;
    __syncthreads();
    for (int d = 1; d < KCODES; d <<= 1) {
        int v = (t >= d) ? s[t - d] : 0;
        __syncthreads();
        s[t] += v;
        __syncthreads();
    }
    cursor[t] = s[t] - my;
    for (int st = 512; st > 0; st >>= 1) {
        if (t < st) rf[t] += rf[t + st];
        __syncthreads();
    }
    float total = rf[0];
    smoothed[t] = (cs + 1e-6f) / (total + 1e-6f * (float)KCODES) * total;
}

// ---- build permutation (1 thread / row) + zero embed_sum ----
__global__ __launch_bounds__(256) void permbuild_kernel(
    const int* __restrict__ ind, int* __restrict__ cursor,
    int* __restrict__ perm, int* __restrict__ codes, uint4* __restrict__ embed_sum4)
{
    const int tid = threadIdx.x;
    // zero 128 uint4 of embed_sum per block (256 blocks x 128 = full 512 KB)
    if (tid < 128) {
        uint4 z = {0, 0, 0, 0};
        embed_sum4[blockIdx.x * 128 + tid] = z;
    }
    const int row = blockIdx.x * 256 + tid;
    const int k = ind[row];
    int pos = atomicAdd(&cursor[k], 1);
    perm[pos] = row;
    codes[pos] = k;
}

// ---- balanced chunked segmented sum (boundary atomics) + fused out_q gather ----
__global__ __launch_bounds__(256) void segsum_kernel(
    const float* __restrict__ x, const float* __restrict__ embed,
    const int* __restrict__ perm, const int* __restrict__ codes,
    float* __restrict__ embed_sum, float* __restrict__ out_q)
{
    const int g = (blockIdx.x * 256 + threadIdx.x) >> 5;   // group id, 0..4095
    const int c = threadIdx.x & 31;                        // lane owns cols 4c..4c+3
    const int base = g * SEG_R;

    float4 acc = {0.f, 0.f, 0.f, 0.f};
    int curk = codes[base];
#pragma unroll
    for (int j = 0; j < SEG_R; ++j) {
        int r = perm[base + j];
        int k = codes[base + j];
        float4 v = *(const float4*)(x + (size_t)r * DIMD + c * 4);
        // fused quantize output: out_q[r] = embed[k]  (embed L2-resident)
        float4 e = *(const float4*)(embed + (size_t)k * DIMD + c * 4);
        *(float4*)(out_q + (size_t)r * DIMD + c * 4) = e;
        if (k != curk) {
            float* dst = embed_sum + (size_t)curk * DIMD + c * 4;
            atomicAdd(dst + 0, acc.x);
            atomicAdd(dst + 1, acc.y);
            atomicAdd(dst + 2, acc.z);
            atomicAdd(dst + 3, acc.w);
            acc = v;
            curk = k;
        } else {
            acc.x += v.x; acc.y += v.y; acc.z += v.z; acc.w += v.w;
        }
    }
    float* dst = embed_sum + (size_t)curk * DIMD + c * 4;
    atomicAdd(dst + 0, acc.x);
    atomicAdd(dst + 1, acc.y);
    atomicAdd(dst + 2, acc.z);
    atomicAdd(dst + 3, acc.w);
}

// ---------------- embed_avg EMA + embed_new ----------------
__global__ void embed_kernel(
    const float* __restrict__ embed_avg, const float* __restrict__ embed_sum,
    const float* __restrict__ smoothed, float* __restrict__ out_ea,
    float* __restrict__ out_en)
{
    int i = blockIdx.x * blockDim.x + threadIdx.x;
    if (i < KCODES * DIMD) {
        float ea = embed_avg[i] * 0.99f + embed_sum[i] * 0.01f;
        out_ea[i] = ea;
        out_en[i] = ea / smoothed[i >> 7];
    }
}

extern "C" void kernel_launch(void* const* d_in, const int* in_sizes, int n_in,
                              void* d_out, int out_size, void* d_ws, size_t ws_size,
                              hipStream_t stream) {
    const float* x            = (const float*)d_in[0];
    const float* embed        = (const float*)d_in[1];
    const float* cluster_size = (const float*)d_in[2];
    const float* embed_avg    = (const float*)d_in[3];

    float* out     = (float*)d_out;
    float* out_q   = out;                       // [65536*128]
    float* out_ind = out + 8388608;             // [65536]
    float* out_cs  = out + 8454144;             // [1024]
    float* out_ea  = out + 8455168;             // [1024*128]
    float* out_en  = out + 8586240;             // [1024*128]

    char* ws = (char*)d_ws;
    int*   ind_i     = (int*)(ws + 0);          // 256 KB
    float* enorm     = (float*)(ws + 262144);   // 4 KB
    int*   countsI   = (int*)(ws + 266240);     // 4 KB  \ zeroed by pre_kernel blk 68
    int*   wl_cnt    = (int*)(ws + 270336);     // 4 KB  /
    int*   cursor    = (int*)(ws + 274432);     // 4 KB
    float* smoothed  = (float*)(ws + 278528);   // 4 KB
    int*   perm      = (int*)(ws + 286720);     // 256 KB
    int*   wl        = (int*)(ws + 548864);     // 256 KB (dead after recheck)
    int*   codes     = (int*)(ws + 548864);     // 256 KB — ALIASES wl (disjoint lifetime)
    uint4* ehg       = (uint4*)(ws + 811008);   // 256 KB f16-hi codebook (dead after argmin)
    float* embed_sum = (float*)(ws + 811008);   // 512 KB — ALIASES ehg (disjoint lifetime;
                                                //          zeroed inside permbuild)

    pre_kernel<<<69, 256, 0, stream>>>(embed, ehg, enorm, (uint4*)countsI);
    argmin_mfma<<<NROWS / 128, 256, 0, stream>>>(
        x, ehg, enorm, ind_i, out_ind, wl, wl_cnt);
    recheck_kernel<<<512, 256, 0, stream>>>(
        x, embed, enorm, wl, wl_cnt, ind_i, out_ind);
    hist_kernel<<<32, 256, 0, stream>>>(ind_i, countsI);
    scan_cluster_kernel<<<1, 1024, 0, stream>>>(countsI, cluster_size, cursor, out_cs, smoothed);
    permbuild_kernel<<<NROWS / 256, 256, 0, stream>>>(
        ind_i, cursor, perm, codes, (uint4*)embed_sum);
    segsum_kernel<<<(NROWS / SEG_R) * 32 / 256, 256, 0, stream>>>(
        x, embed, perm, codes, embed_sum, out_q);
    embed_kernel<<<(KCODES * DIMD + 255) / 256, 256, 0, stream>>>(
        embed_avg, embed_sum, smoothed, out_ea, out_en);
}

// Round 9
// 242.978 us; speedup vs baseline: 1.6241x; 1.6241x over previous
//
#include <hip/hip_runtime.h>
#include <hip/hip_fp16.h>
#include <float.h>

#define DIMD   128
#define KCODES 1024
#define NROWS  65536
#define TAU    0.03f
#define SEG_R  16    // rows per segsum group

typedef __attribute__((ext_vector_type(8)))  _Float16 half8;
typedef __attribute__((ext_vector_type(16))) float f32x16;

union U8 { uint4 u; half8 h; };

__device__ __forceinline__ unsigned packh2(float a, float b) {
    __half2 t = __floats2half2_rn(a, b);
    return *(unsigned*)&t;
}

// ---- fused: preconvert codebook f16-hi (blocks 0..63) + enorm (64..67) + zero counts (68) ----
__global__ __launch_bounds__(256) void pre_kernel(
    const float* __restrict__ embed, uint4* __restrict__ ehg,
    float* __restrict__ enorm, uint4* __restrict__ zero_region)
{
    if (blockIdx.x < 64) {
        int t = blockIdx.x * 256 + threadIdx.x;     // 0..16383
        int chunk = t >> 9;
        int s = (t >> 6) & 7;
        int L = t & 63;
        const float* src = embed + ((size_t)(chunk * 32 + (L & 31)) * DIMD) + s * 16 + (L >> 5) * 8;
        float4 a = *(const float4*)src;
        float4 b = *(const float4*)(src + 4);
        float f[8] = {a.x, a.y, a.z, a.w, b.x, b.y, b.z, b.w};
        uint4 H;
        unsigned* hw = (unsigned*)&H;
#pragma unroll
        for (int j = 0; j < 4; ++j) hw[j] = packh2(f[2 * j], f[2 * j + 1]);
        ehg[t] = H;
    } else if (blockIdx.x < 68) {
        int k = (blockIdx.x - 64) * 256 + threadIdx.x;
        const float4* e = (const float4*)(embed + (size_t)k * DIMD);
        float s = 0.f;
#pragma unroll
        for (int c = 0; c < DIMD / 4; ++c) {
            float4 v = e[c];
            s += v.x * v.x + v.y * v.y + v.z * v.z + v.w * v.w;
        }
        enorm[k] = s;
    } else {
        uint4 z = {0, 0, 0, 0};
        zero_region[threadIdx.x] = z;
        zero_region[threadIdx.x + 256] = z;
    }
}

// ---------------- fused MFMA distance (f16 2-term: (xh+xl)·eh) + argmin (top-2) ----------------
// __launch_bounds__(256,2): VGPR cap 256 — kernel needs ~130 (64 A-frags + 48 top2 + 16 acc).
// (256,3) capped VGPRs at 84 and spilled ~2.5KB/thread -> 0.5GB scratch traffic (R8 regression).
__global__ __launch_bounds__(256, 2) void argmin_mfma(
    const float* __restrict__ x, const uint4* __restrict__ ehg,
    const float* __restrict__ enorm,
    int* __restrict__ ind_i, float* __restrict__ ind_f,
    int* __restrict__ wl, int* __restrict__ wl_cnt)
{
    __shared__ uint4 Bs[512];     // one chunk of eh f16 frags (8 KB)

    const int tid  = threadIdx.x;
    const int wave = tid >> 6;
    const int lane = tid & 63;
    const int n    = lane & 31;
    const int h    = lane >> 5;
    const int row0 = blockIdx.x * 128;
    const int rowA = row0 + wave * 32 + n;

    // A fragments: x split into f16 hi/lo, held in regs for all 8 k-steps
    uint4 xh[8], xl[8];
    const float* xrow = x + (size_t)rowA * DIMD + h * 8;
#pragma unroll
    for (int s = 0; s < 8; ++s) {
        float4 a = *(const float4*)(xrow + s * 16);
        float4 b = *(const float4*)(xrow + s * 16 + 4);
        float f[8] = {a.x, a.y, a.z, a.w, b.x, b.y, b.z, b.w};
        unsigned* ph = (unsigned*)&xh[s];
        unsigned* pl = (unsigned*)&xl[s];
#pragma unroll
        for (int j = 0; j < 4; ++j) {
            float u0 = f[2 * j], u1 = f[2 * j + 1];
            __half2 hh = __floats2half2_rn(u0, u1);
            ph[j] = *(unsigned*)&hh;
            float2 back = __half22float2(hh);
            __half2 ll = __floats2half2_rn(u0 - back.x, u1 - back.y);
            pl[j] = *(unsigned*)&ll;
        }
    }

    float bestv[16], best2[16];
    int   besti[16];
#pragma unroll
    for (int r = 0; r < 16; ++r) { bestv[r] = FLT_MAX; best2[r] = FLT_MAX; besti[r] = 0; }

    for (int chunk = 0; chunk < KCODES / 32; ++chunk) {
        __syncthreads();   // previous chunk's Bs reads done
        {
            const uint4* sh = ehg + chunk * 512;
            Bs[tid]       = sh[tid];
            Bs[tid + 256] = sh[tid + 256];
        }
        float ee_val = enorm[chunk * 32 + n];
        __syncthreads();

        f32x16 acc;
#pragma unroll
        for (int r = 0; r < 16; ++r) acc[r] = 0.f;

#pragma unroll
        for (int s = 0; s < 8; ++s) {
            U8 ah, al, bh;
            ah.u = xh[s]; al.u = xl[s];
            bh.u = Bs[s * 64 + lane];
            acc = __builtin_amdgcn_mfma_f32_32x32x16_f16(ah.h, bh.h, acc, 0, 0, 0);
            acc = __builtin_amdgcn_mfma_f32_32x32x16_f16(al.h, bh.h, acc, 0, 0, 0);
        }

        const int nglob = chunk * 32 + n;
#pragma unroll
        for (int r = 0; r < 16; ++r) {
            float d = fmaf(-2.f, acc[r], ee_val);
            bool c1 = d < bestv[r];
            float t = c1 ? bestv[r] : d;
            best2[r] = fminf(best2[r], t);
            besti[r] = c1 ? nglob : besti[r];
            bestv[r] = fminf(bestv[r], d);
        }
    }

    // cross-lane (32 columns) top-2 merge via butterfly
#pragma unroll
    for (int m = 1; m <= 16; m <<= 1) {
#pragma unroll
        for (int r = 0; r < 16; ++r) {
            float ov = __shfl_xor(bestv[r], m, 64);
            float o2 = __shfl_xor(best2[r], m, 64);
            int   oi = __shfl_xor(besti[r], m, 64);
            float hi = fmaxf(bestv[r], ov);
            best2[r] = fminf(fminf(best2[r], o2), hi);
            bool take = (ov < bestv[r]) || (ov == bestv[r] && oi < besti[r]);
            bestv[r] = take ? ov : bestv[r];
            besti[r] = take ? oi : besti[r];
        }
    }

    if (n == 0) {
#pragma unroll
        for (int r = 0; r < 16; ++r) {
            int row = row0 + wave * 32 + (r & 3) + 8 * (r >> 2) + 4 * h;
            ind_i[row] = besti[r];
            ind_f[row] = (float)besti[r];
            if (best2[r] - bestv[r] < TAU) {
                int p = atomicAdd(wl_cnt, 1);
                if (p < NROWS) wl[p] = row;
            }
        }
    }
}

// ---------------- exact fp32 re-check for near-tie rows (fixes ind only) ----------------
__global__ __launch_bounds__(256) void recheck_kernel(
    const float* __restrict__ x, const float* __restrict__ embed,
    const float* __restrict__ enorm, const int* __restrict__ wl,
    const int* __restrict__ wl_cnt, int* __restrict__ ind_i, float* __restrict__ ind_f)
{
    __shared__ float xs[DIMD];
    __shared__ float rv[256];
    __shared__ int   ri[256];
    const int tid = threadIdx.x;
    int count = *wl_cnt;
    if (count > NROWS) count = NROWS;

    for (int i = blockIdx.x; i < count; i += gridDim.x) {
        const int row = wl[i];
        __syncthreads();
        if (tid < DIMD) xs[tid] = x[(size_t)row * DIMD + tid];
        __syncthreads();

        const float4* xs4 = (const float4*)xs;
        float xn = 0.f;
#pragma unroll 8
        for (int c = 0; c < 32; ++c) {
            float4 v = xs4[c];
            xn += v.x * v.x + v.y * v.y + v.z * v.z + v.w * v.w;
        }

        float bv = FLT_MAX; int bi = 0;
#pragma unroll
        for (int c = 0; c < 4; ++c) {
            int code = tid * 4 + c;
            const float4* er = (const float4*)(embed + (size_t)code * DIMD);
            float acc = 0.f;
#pragma unroll 8
            for (int kk = 0; kk < 32; ++kk) {
                float4 a = xs4[kk];
                float4 b = er[kk];
                acc += a.x * b.x + a.y * b.y + a.z * b.z + a.w * b.w;
            }
            float d = (xn - 2.0f * acc) + enorm[code];
            if (d < bv) { bv = d; bi = code; }
        }
        rv[tid] = bv; ri[tid] = bi;
        __syncthreads();
        for (int s = 128; s > 0; s >>= 1) {
            if (tid < s) {
                if (rv[tid + s] < rv[tid] || (rv[tid + s] == rv[tid] && ri[tid + s] < ri[tid])) {
                    rv[tid] = rv[tid + s]; ri[tid] = ri[tid + s];
                }
            }
            __syncthreads();
        }
        if (tid == 0) {
            int s_new = ri[0];
            if (s_new != ind_i[row]) {
                ind_i[row] = s_new;
                ind_f[row] = (float)s_new;
            }
        }
        __syncthreads();
    }
}

// ---------------- histogram of final code assignments (LDS-aggregated) ----------------
__global__ __launch_bounds__(256) void hist_kernel(
    const int* __restrict__ ind, int* __restrict__ counts)
{
    __shared__ int hcnt[KCODES];
    for (int i = threadIdx.x; i < KCODES; i += 256) hcnt[i] = 0;
    __syncthreads();
    const int base = blockIdx.x * 2048;
    for (int i = threadIdx.x; i < 2048; i += 256) atomicAdd(&hcnt[ind[base + i]], 1);
    __syncthreads();
    for (int i = threadIdx.x; i < KCODES; i += 256) {
        int v = hcnt[i];
        if (v) atomicAdd(&counts[i], v);
    }
}

// ---------------- fused: exclusive scan (cursor) + cluster EMA + smoothed ----------------
__global__ __launch_bounds__(1024) void scan_cluster_kernel(
    const int* __restrict__ counts, const float* __restrict__ cluster_size,
    int* __restrict__ cursor, float* __restrict__ out_cs, float* __restrict__ smoothed)
{
    __shared__ int   s[KCODES];
    __shared__ float rf[KCODES];
    const int t = threadIdx.x;
    int my = counts[t];
    s[t] = my;
    float cs = cluster_size[t] * 0.99f + (float)my * 0.01f;
    out_cs[t] = cs;
    rf[t] = cs;
    __syncthreads();
    for (int d = 1; d < KCODES; d <<= 1) {
        int v = (t >= d) ? s[t - d] : 0;
        __syncthreads();
        s[t] += v;
        __syncthreads();
    }
    cursor[t] = s[t] - my;
    for (int st = 512; st > 0; st >>= 1) {
        if (t < st) rf[t] += rf[t + st];
        __syncthreads();
    }
    float total = rf[0];
    smoothed[t] = (cs + 1e-6f) / (total + 1e-6f * (float)KCODES) * total;
}

// ---- build permutation (1 thread / row) + zero embed_sum ----
__global__ __launch_bounds__(256) void permbuild_kernel(
    const int* __restrict__ ind, int* __restrict__ cursor,
    int* __restrict__ perm, int* __restrict__ codes, uint4* __restrict__ embed_sum4)
{
    const int tid = threadIdx.x;
    // zero 128 uint4 of embed_sum per block (256 blocks x 128 = full 512 KB)
    if (tid < 128) {
        uint4 z = {0, 0, 0, 0};
        embed_sum4[blockIdx.x * 128 + tid] = z;
    }
    const int row = blockIdx.x * 256 + tid;
    const int k = ind[row];
    int pos = atomicAdd(&cursor[k], 1);
    perm[pos] = row;
    codes[pos] = k;
}

// ---- balanced chunked segmented sum (boundary atomics) + fused out_q gather ----
__global__ __launch_bounds__(256) void segsum_kernel(
    const float* __restrict__ x, const float* __restrict__ embed,
    const int* __restrict__ perm, const int* __restrict__ codes,
    float* __restrict__ embed_sum, float* __restrict__ out_q)
{
    const int g = (blockIdx.x * 256 + threadIdx.x) >> 5;   // group id, 0..4095
    const int c = threadIdx.x & 31;                        // lane owns cols 4c..4c+3
    const int base = g * SEG_R;

    float4 acc = {0.f, 0.f, 0.f, 0.f};
    int curk = codes[base];
#pragma unroll
    for (int j = 0; j < SEG_R; ++j) {
        int r = perm[base + j];
        int k = codes[base + j];
        float4 v = *(const float4*)(x + (size_t)r * DIMD + c * 4);
        // fused quantize output: out_q[r] = embed[k]  (embed L2-resident)
        float4 e = *(const float4*)(embed + (size_t)k * DIMD + c * 4);
        *(float4*)(out_q + (size_t)r * DIMD + c * 4) = e;
        if (k != curk) {
            float* dst = embed_sum + (size_t)curk * DIMD + c * 4;
            atomicAdd(dst + 0, acc.x);
            atomicAdd(dst + 1, acc.y);
            atomicAdd(dst + 2, acc.z);
            atomicAdd(dst + 3, acc.w);
            acc = v;
            curk = k;
        } else {
            acc.x += v.x; acc.y += v.y; acc.z += v.z; acc.w += v.w;
        }
    }
    float* dst = embed_sum + (size_t)curk * DIMD + c * 4;
    atomicAdd(dst + 0, acc.x);
    atomicAdd(dst + 1, acc.y);
    atomicAdd(dst + 2, acc.z);
    atomicAdd(dst + 3, acc.w);
}

// ---------------- embed_avg EMA + embed_new ----------------
__global__ void embed_kernel(
    const float* __restrict__ embed_avg, const float* __restrict__ embed_sum,
    const float* __restrict__ smoothed, float* __restrict__ out_ea,
    float* __restrict__ out_en)
{
    int i = blockIdx.x * blockDim.x + threadIdx.x;
    if (i < KCODES * DIMD) {
        float ea = embed_avg[i] * 0.99f + embed_sum[i] * 0.01f;
        out_ea[i] = ea;
        out_en[i] = ea / smoothed[i >> 7];
    }
}

extern "C" void kernel_launch(void* const* d_in, const int* in_sizes, int n_in,
                              void* d_out, int out_size, void* d_ws, size_t ws_size,
                              hipStream_t stream) {
    const float* x            = (const float*)d_in[0];
    const float* embed        = (const float*)d_in[1];
    const float* cluster_size = (const float*)d_in[2];
    const float* embed_avg    = (const float*)d_in[3];

    float* out     = (float*)d_out;
    float* out_q   = out;                       // [65536*128]
    float* out_ind = out + 8388608;             // [65536]
    float* out_cs  = out + 8454144;             // [1024]
    float* out_ea  = out + 8455168;             // [1024*128]
    float* out_en  = out + 8586240;             // [1024*128]

    char* ws = (char*)d_ws;
    int*   ind_i     = (int*)(ws + 0);          // 256 KB
    float* enorm     = (float*)(ws + 262144);   // 4 KB
    int*   countsI   = (int*)(ws + 266240);     // 4 KB  \ zeroed by pre_kernel blk 68
    int*   wl_cnt    = (int*)(ws + 270336);     // 4 KB  /
    int*   cursor    = (int*)(ws + 274432);     // 4 KB
    float* smoothed  = (float*)(ws + 278528);   // 4 KB
    int*   perm      = (int*)(ws + 286720);     // 256 KB
    int*   wl        = (int*)(ws + 548864);     // 256 KB (dead after recheck)
    int*   codes     = (int*)(ws + 548864);     // 256 KB — ALIASES wl (disjoint lifetime)
    uint4* ehg       = (uint4*)(ws + 811008);   // 256 KB f16-hi codebook (dead after argmin)
    float* embed_sum = (float*)(ws + 811008);   // 512 KB — ALIASES ehg (disjoint lifetime;
                                                //          zeroed inside permbuild)

    pre_kernel<<<69, 256, 0, stream>>>(embed, ehg, enorm, (uint4*)countsI);
    argmin_mfma<<<NROWS / 128, 256, 0, stream>>>(
        x, ehg, enorm, ind_i, out_ind, wl, wl_cnt);
    recheck_kernel<<<512, 256, 0, stream>>>(
        x, embed, enorm, wl, wl_cnt, ind_i, out_ind);
    hist_kernel<<<32, 256, 0, stream>>>(ind_i, countsI);
    scan_cluster_kernel<<<1, 1024, 0, stream>>>(countsI, cluster_size, cursor, out_cs, smoothed);
    permbuild_kernel<<<NROWS / 256, 256, 0, stream>>>(
        ind_i, cursor, perm, codes, (uint4*)embed_sum);
    segsum_kernel<<<(NROWS / SEG_R) * 32 / 256, 256, 0, stream>>>(
        x, embed, perm, codes, embed_sum, out_q);
    embed_kernel<<<(KCODES * DIMD + 255) / 256, 256, 0, stream>>>(
        embed_avg, embed_sum, smoothed, out_ea, out_en);
}